// Round 15
// baseline (59.958 us; speedup 1.0000x reference)
//
#include <hip/hip_runtime.h>

// Legendre2 v15: 2-blocks/CU probe. v14 inner loop (51.4us) unchanged;
// LDS squeezed to EXACTLY 64 KiB so two 8-wave blocks co-reside per CU
// (prior attempts never isolated this: R6 spilled, R7/R8 added barriers):
//   - BH A-table 48 KB (unchanged)
//   - transpose scratch 2 KB/wave (two k-32 phases, R5-verified variant)
//   - scales ALIASED into scratch (only live before the main loop)
//   - C-fragments in 16 REGISTERS (each lane loads its own C elems from
//     global; same values as the old LDS path)
// Grid 512 blocks x 512 thr; each wave owns 128 rows (4 iters). Numerics
// byte-identical to v14 -> absmax must stay 16777220.
// N=524288, D=64, K=64, O=32, DEGREE=6.

typedef _Float16 f16x8 __attribute__((ext_vector_type(8)));
typedef short    s16x8 __attribute__((ext_vector_type(8)));
typedef float    f32x4 __attribute__((ext_vector_type(4)));

#define NN      524288
#define BLOCKS  512
#define THREADS 512
#define NWAVES  8
#define NITER   4                        // 4 x 32-row tiles per wave

// LDS byte offsets
#define BH_OFF  0                        // 48 frags * 1 KB (f16 of A)
#define SCR_OFF 49152                    // 8 waves * 2 KB scratch (scales alias)
#define SMEM_BYTES 65536                 // exactly 64 KiB -> 2 blocks/CU

__device__ __forceinline__ unsigned short f2bf(float x) {
    unsigned u = __builtin_bit_cast(unsigned, x);
    return (unsigned short)((u + 0x7FFFu + ((u >> 16) & 1u)) >> 16);
}

__global__ __launch_bounds__(THREADS) void leg_mfma(
    const float* __restrict__ z, const float* __restrict__ T,
    const float* __restrict__ Cm, const float* __restrict__ beta,
    float* __restrict__ out)
{
    extern __shared__ char smem[];
    float* scale_s = (float*)(smem + SCR_OFF);   // aliased; dead after staging
    const int tid  = (int)threadIdx.x;
    const int lane = tid & 63;
    const int wv   = tid >> 6;
    const int lrow = lane & 15;          // row (A-op) / col (C/D) index
    const int lhi  = lane >> 4;          // 0..3

    // ---------- C-operand frags -> REGISTERS (bf16 single-term) -------------
    // frag(s,fo): lane l supplies C2[k=32s+lhi*8+j][o=(l&15)+16fo] = C[o][k].
    s16x8 ch[2][2];
    #pragma unroll
    for (int s = 0; s < 2; ++s)
        #pragma unroll
        for (int fo = 0; fo < 2; ++fo) {
            const int o  = lrow + (fo << 4);
            const int k0 = (lhi << 3) + (s << 5);
            const float4 v0 = *(const float4*)(Cm + (size_t)o * 64 + k0);
            const float4 v1 = *(const float4*)(Cm + (size_t)o * 64 + k0 + 4);
            const float vv[8] = {v0.x, v0.y, v0.z, v0.w, v1.x, v1.y, v1.z, v1.w};
            s16x8 fr;
            #pragma unroll
            for (int j = 0; j < 8; ++j) fr[j] = (short)f2bf(vv[j]);
            ch[s][fo] = fr;
        }

    // ---------- phase A: per-row scales: j==0 -> 1, else coef_j / rowsum ----
    if (tid < 384) {
        const int mat = tid >> 6, kc = tid & 63;
        const float4* tr = (const float4*)(T + (size_t)((mat << 6) + kc) * 64);
        float s = 0.f;
        #pragma unroll
        for (int q = 0; q < 16; ++q) { float4 v = tr[q]; s += v.x + v.y + v.z + v.w; }
        float sc;
        if (mat == 0) sc = 1.f;
        else { const float fi = (float)(mat + 1); sc = (2.f * fi - 1.f) / fi / s; }
        scale_s[tid] = sc;
    }
    __syncthreads();

    // ---------- phase B: build B-operand frags of A (f16, single term) ------
    for (int g = tid; g < 3072; g += THREADS) {
        const int mat = g >> 9;
        const int s   = (g >> 8) & 1;
        const int f   = (g >> 6) & 3;
        const int l   = g & 63;
        const int kc  = (l & 15) + (f << 4);
        const int d0  = ((l >> 4) << 3) + (s << 5);
        const float sc = scale_s[(mat << 6) + kc];
        const float* src = T + (size_t)((mat << 6) + kc) * 64 + d0;
        const float4 v0 = *(const float4*)(src);
        const float4 v1 = *(const float4*)(src + 4);
        const float vv[8] = {v0.x, v0.y, v0.z, v0.w, v1.x, v1.y, v1.z, v1.w};
        f16x8 hi;
        #pragma unroll
        for (int j = 0; j < 8; ++j) hi[j] = (_Float16)(vv[j] * sc);
        const int fr = (((mat << 1) + s) << 2) + f;
        *(f16x8*)(smem + BH_OFF + fr * 1024 + l * 16) = hi;
    }
    __syncthreads();                     // scales dead; scratch now owns region

    // ---------- main: each wave owns 128 rows, 4 iters of 32 rows -----------
    const int    gw      = blockIdx.x * NWAVES + wv;
    const size_t rowbase = (size_t)gw * 128;
    float* scr = (float*)(smem + SCR_OFF) + wv * 512;   // 16 rows x 32 f32

    const float beta0 = beta[lrow];
    const float beta1 = beta[16 + lrow];

    f16x8 zh[2][2];

    // one Legendre level: PT := a * PC - b * PT, a = chained k-half MFMAs
    auto leg_step = [&](int mat, float b, f32x4 (&PC)[2][4], f32x4 (&PT)[2][4]) {
        __builtin_amdgcn_s_setprio(1);
        #pragma unroll
        for (int f = 0; f < 4; ++f) {
            const int fr0 = mat * 8 + f;       // s=0
            const int fr1 = mat * 8 + 4 + f;   // s=1
            const f16x8 bh0 = *(const f16x8*)(smem + BH_OFF + fr0 * 1024 + lane * 16);
            const f16x8 bh1 = *(const f16x8*)(smem + BH_OFF + fr1 * 1024 + lane * 16);
            #pragma unroll
            for (int t = 0; t < 2; ++t) {
                f32x4 a = {0.f, 0.f, 0.f, 0.f};
                a = __builtin_amdgcn_mfma_f32_16x16x32_f16(zh[t][0], bh0, a, 0, 0, 0);
                a = __builtin_amdgcn_mfma_f32_16x16x32_f16(zh[t][1], bh1, a, 0, 0, 0);
                #pragma unroll
                for (int r = 0; r < 4; ++r)
                    PT[t][f][r] = a[r] * PC[t][f][r] - b * PT[t][f][r];
            }
        }
        __builtin_amdgcn_s_setprio(0);
    };

    // prologue: load z for iter 0
    float4 zraw[2][4];
    #pragma unroll
    for (int t = 0; t < 2; ++t)
        #pragma unroll
        for (int s = 0; s < 2; ++s) {
            const float* p = z + (rowbase + t * 16 + lrow) * 64 + (s << 5) + (lhi << 3);
            zraw[t][2 * s]     = *(const float4*)(p);
            zraw[t][2 * s + 1] = *(const float4*)(p + 4);
        }

    for (int it = 0; it < NITER; ++it) {
        // convert staged z to f16 fragments
        #pragma unroll
        for (int t = 0; t < 2; ++t)
            #pragma unroll
            for (int s = 0; s < 2; ++s) {
                const float4 q0 = zraw[t][2 * s], q1 = zraw[t][2 * s + 1];
                const float vv[8] = {q0.x, q0.y, q0.z, q0.w, q1.x, q1.y, q1.z, q1.w};
                #pragma unroll
                for (int j = 0; j < 8; ++j) zh[t][s][j] = (_Float16)vv[j];
            }
        // prefetch next iter's z (in flight across the mat loop)
        if (it < NITER - 1) {
            #pragma unroll
            for (int t = 0; t < 2; ++t)
                #pragma unroll
                for (int s = 0; s < 2; ++s) {
                    const float* p = z + (rowbase + (it + 1) * 32 + t * 16 + lrow) * 64
                                       + (s << 5) + (lhi << 3);
                    zraw[t][2 * s]     = *(const float4*)(p);
                    zraw[t][2 * s + 1] = *(const float4*)(p + 4);
                }
        }

        // Legendre chain: pA = P1, pB = P2, then ping-pong; P6 ends in pB
        f32x4 pA[2][4], pB[2][4];
        // mat 0 -> pA  (P1), chained
        __builtin_amdgcn_s_setprio(1);
        #pragma unroll
        for (int f = 0; f < 4; ++f) {
            const int fr0 = f, fr1 = 4 + f;
            const f16x8 bh0 = *(const f16x8*)(smem + BH_OFF + fr0 * 1024 + lane * 16);
            const f16x8 bh1 = *(const f16x8*)(smem + BH_OFF + fr1 * 1024 + lane * 16);
            #pragma unroll
            for (int t = 0; t < 2; ++t) {
                f32x4 a = {0.f, 0.f, 0.f, 0.f};
                a = __builtin_amdgcn_mfma_f32_16x16x32_f16(zh[t][0], bh0, a, 0, 0, 0);
                a = __builtin_amdgcn_mfma_f32_16x16x32_f16(zh[t][1], bh1, a, 0, 0, 0);
                pA[t][f] = a;
            }
        }
        // mat 1 -> pB = W2*pA - 0.5  (P2; P0 = ones)
        #pragma unroll
        for (int f = 0; f < 4; ++f) {
            const int fr0 = 8 + f, fr1 = 12 + f;
            const f16x8 bh0 = *(const f16x8*)(smem + BH_OFF + fr0 * 1024 + lane * 16);
            const f16x8 bh1 = *(const f16x8*)(smem + BH_OFF + fr1 * 1024 + lane * 16);
            #pragma unroll
            for (int t = 0; t < 2; ++t) {
                f32x4 a = {0.f, 0.f, 0.f, 0.f};
                a = __builtin_amdgcn_mfma_f32_16x16x32_f16(zh[t][0], bh0, a, 0, 0, 0);
                a = __builtin_amdgcn_mfma_f32_16x16x32_f16(zh[t][1], bh1, a, 0, 0, 0);
                #pragma unroll
                for (int r = 0; r < 4; ++r)
                    pB[t][f][r] = a[r] * pA[t][f][r] - 0.5f;
            }
        }
        __builtin_amdgcn_s_setprio(0);
        leg_step(2, 2.f / 3.f, pB, pA);   // P3
        leg_step(3, 3.f / 4.f, pA, pB);   // P4
        leg_step(4, 4.f / 5.f, pB, pA);   // P5
        leg_step(5, 5.f / 6.f, pA, pB);   // P6 = pB

        // ---------------- epilogue: out = P6 @ C^T + beta (single-term) -----
        // transpose P6 -> A-op layout, two k-32 phases through 16x32 scratch
        #pragma unroll
        for (int t = 0; t < 2; ++t) {
            s16x8 p6h[2];
            #pragma unroll
            for (int s = 0; s < 2; ++s) {
                #pragma unroll
                for (int f_ = 0; f_ < 2; ++f_) {
                    const int f    = 2 * s + f_;
                    const int colp = (f_ << 4) + lrow;
                    #pragma unroll
                    for (int r = 0; r < 4; ++r) {
                        const int row = lhi * 4 + r;
                        const int g4  = ((colp >> 2) ^ row) & 7;
                        scr[row * 32 + g4 * 4 + (colp & 3)] = pB[t][f][r];
                    }
                }
                // wave-synchronous read-back (compiler inserts lgkmcnt wait)
                float vv[8];
                #pragma unroll
                for (int jg = 0; jg < 2; ++jg) {
                    const int g4r = (((lhi << 1) + jg) ^ lrow) & 7;
                    const float4 q = *(const float4*)(scr + lrow * 32 + g4r * 4);
                    vv[jg * 4 + 0] = q.x; vv[jg * 4 + 1] = q.y;
                    vv[jg * 4 + 2] = q.z; vv[jg * 4 + 3] = q.w;
                }
                #pragma unroll
                for (int j = 0; j < 8; ++j) p6h[s][j] = (short)f2bf(vv[j]);
            }
            #pragma unroll
            for (int fo = 0; fo < 2; ++fo) {
                f32x4 o = {0.f, 0.f, 0.f, 0.f};
                o = __builtin_amdgcn_mfma_f32_16x16x32_bf16(p6h[0], ch[0][fo], o, 0, 0, 0);
                o = __builtin_amdgcn_mfma_f32_16x16x32_bf16(p6h[1], ch[1][fo], o, 0, 0, 0);
                const float bb = fo ? beta1 : beta0;
                const size_t r0 = rowbase + (size_t)it * 32 + t * 16 + lhi * 4;
                #pragma unroll
                for (int r = 0; r < 4; ++r)
                    out[(r0 + r) * 32 + (fo << 4) + lrow] = o[r] + bb;
            }
        }
    }
}

extern "C" void kernel_launch(void* const* d_in, const int* in_sizes, int n_in,
                              void* d_out, int out_size, void* d_ws, size_t ws_size,
                              hipStream_t stream) {
    const float* z    = (const float*)d_in[0];
    const float* T    = (const float*)d_in[1];
    const float* C    = (const float*)d_in[2];
    const float* beta = (const float*)d_in[3];
    float* out = (float*)d_out;
    (void)in_sizes; (void)n_in; (void)out_size; (void)d_ws; (void)ws_size;

    hipFuncSetAttribute((const void*)leg_mfma,
                        hipFuncAttributeMaxDynamicSharedMemorySize, SMEM_BYTES);
    leg_mfma<<<BLOCKS, THREADS, SMEM_BYTES, stream>>>(z, T, C, beta, out);
}

// Round 16
// 51.634 us; speedup vs baseline: 1.1612x; 1.1612x over previous
//
#include <hip/hip_runtime.h>

// Legendre2 v16: 2-tile B-frag amortization on v14 (51.4us best).
// Each wave: 4 iters x 64 rows (two 32-row tiles u=0,1). Per level the 8
// B-frag ds_read_b128 are loaded ONCE and feed 4 accumulator quartets
// (u x t) -> LDS traffic per row HALVES (the fattest reducible pipe,
// ~15us of the 51). Register budget: v14's 84 + 16 zh + 32 acc, minus the
// dropped zraw prefetch double-buffer (R4: prefetch ~neutral) ~= 116 < 128.
// Numerics byte-identical to v14 -> absmax must stay 16777220.
// Structure: 256 blocks x 512 thr, 8 waves x 256 rows, A-table f16 single
// term in LDS, chained k-half MFMA, setprio on MFMA clusters, single-term
// bf16 epilogue. N=524288, D=64, K=64, O=32, DEGREE=6.

typedef _Float16 f16x8 __attribute__((ext_vector_type(8)));
typedef short    s16x8 __attribute__((ext_vector_type(8)));
typedef float    f32x4 __attribute__((ext_vector_type(4)));

#define NN      524288
#define BLOCKS  256
#define THREADS 512
#define NWAVES  8
#define NITER   4                        // 4 x 64-row (2-tile) passes per wave

// LDS byte offsets
#define BH_OFF    0                      // 48 frags * 1 KB (f16 of A)
#define CF_OFF    49152                  // 4 frags * 1 KB (bf16 hi of C)
#define SCALE_OFF 53248                  // 384 f32 scales
#define SCR_OFF   54784                  // 8 waves * 4 KB transpose scratch
#define SMEM_BYTES (SCR_OFF + NWAVES * 4096)   // 87552 B

__device__ __forceinline__ unsigned short f2bf(float x) {
    unsigned u = __builtin_bit_cast(unsigned, x);
    return (unsigned short)((u + 0x7FFFu + ((u >> 16) & 1u)) >> 16);
}

__global__ __launch_bounds__(THREADS) void leg_mfma(
    const float* __restrict__ z, const float* __restrict__ T,
    const float* __restrict__ Cm, const float* __restrict__ beta,
    float* __restrict__ out)
{
    extern __shared__ char smem[];
    float* scale_s = (float*)(smem + SCALE_OFF);
    const int tid  = (int)threadIdx.x;
    const int lane = tid & 63;
    const int wv   = tid >> 6;
    const int lrow = lane & 15;          // row (A-op) / col (C/D) index
    const int lhi  = lane >> 4;          // 0..3

    // ---------- phase A: per-row scales: j==0 -> 1, else coef_j / rowsum ----
    if (tid < 384) {
        const int mat = tid >> 6, kc = tid & 63;
        const float4* tr = (const float4*)(T + (size_t)((mat << 6) + kc) * 64);
        float s = 0.f;
        #pragma unroll
        for (int q = 0; q < 16; ++q) { float4 v = tr[q]; s += v.x + v.y + v.z + v.w; }
        float sc;
        if (mat == 0) sc = 1.f;
        else { const float fi = (float)(mat + 1); sc = (2.f * fi - 1.f) / fi / s; }
        scale_s[tid] = sc;
    }
    __syncthreads();

    // ---------- phase B: build B-operand frags of A (f16, single term) ------
    for (int g = tid; g < 3072; g += THREADS) {
        const int mat = g >> 9;
        const int s   = (g >> 8) & 1;
        const int f   = (g >> 6) & 3;
        const int l   = g & 63;
        const int kc  = (l & 15) + (f << 4);
        const int d0  = ((l >> 4) << 3) + (s << 5);
        const float sc = scale_s[(mat << 6) + kc];
        const float* src = T + (size_t)((mat << 6) + kc) * 64 + d0;
        const float4 v0 = *(const float4*)(src);
        const float4 v1 = *(const float4*)(src + 4);
        const float vv[8] = {v0.x, v0.y, v0.z, v0.w, v1.x, v1.y, v1.z, v1.w};
        f16x8 hi;
        #pragma unroll
        for (int j = 0; j < 8; ++j) hi[j] = (_Float16)(vv[j] * sc);
        const int fr = (((mat << 1) + s) << 2) + f;
        *(f16x8*)(smem + BH_OFF + fr * 1024 + l * 16) = hi;
    }
    // C-operand frags (bf16 single-term)
    if (tid < 256) {
        const int s  = (tid >> 7) & 1;
        const int fo = (tid >> 6) & 1;
        const int l  = tid & 63;
        const int o  = (l & 15) + (fo << 4);
        const int k0 = ((l >> 4) << 3) + (s << 5);
        const float* src = Cm + (size_t)o * 64 + k0;
        const float4 v0 = *(const float4*)src;
        const float4 v1 = *(const float4*)(src + 4);
        const float vv[8] = {v0.x, v0.y, v0.z, v0.w, v1.x, v1.y, v1.z, v1.w};
        s16x8 fr;
        #pragma unroll
        for (int j = 0; j < 8; ++j) fr[j] = (short)f2bf(vv[j]);
        *(s16x8*)(smem + CF_OFF + ((s << 1) + fo) * 1024 + l * 16) = fr;
    }
    __syncthreads();

    // ---------- main: each wave owns 256 rows, 4 iters of 64 rows -----------
    const int    gw      = blockIdx.x * NWAVES + wv;
    const size_t rowbase = (size_t)gw * 256;
    float* scr = (float*)(smem + SCR_OFF + wv * 4096);

    const float beta0 = beta[lrow];
    const float beta1 = beta[16 + lrow];

    f16x8 zh[2][2][2];                   // [u][t][s]

    // one Legendre level: B-frags read ONCE, applied to 4 quartets (u,t).
    // PT := a * PC - b * PT, a = chained k-half MFMAs.
    auto leg_step = [&](int mat, float b,
                        f32x4 (&PC)[2][2][4], f32x4 (&PT)[2][2][4]) {
        __builtin_amdgcn_s_setprio(1);
        #pragma unroll
        for (int f = 0; f < 4; ++f) {
            const int fr0 = mat * 8 + f;       // s=0
            const int fr1 = mat * 8 + 4 + f;   // s=1
            const f16x8 bh0 = *(const f16x8*)(smem + BH_OFF + fr0 * 1024 + lane * 16);
            const f16x8 bh1 = *(const f16x8*)(smem + BH_OFF + fr1 * 1024 + lane * 16);
            #pragma unroll
            for (int u = 0; u < 2; ++u)
                #pragma unroll
                for (int t = 0; t < 2; ++t) {
                    f32x4 a = {0.f, 0.f, 0.f, 0.f};
                    a = __builtin_amdgcn_mfma_f32_16x16x32_f16(zh[u][t][0], bh0, a, 0, 0, 0);
                    a = __builtin_amdgcn_mfma_f32_16x16x32_f16(zh[u][t][1], bh1, a, 0, 0, 0);
                    #pragma unroll
                    for (int r = 0; r < 4; ++r)
                        PT[u][t][f][r] = a[r] * PC[u][t][f][r] - b * PT[u][t][f][r];
                }
        }
        __builtin_amdgcn_s_setprio(0);
    };

    for (int it = 0; it < NITER; ++it) {
        // load + convert z for both tiles (no persistent double-buffer:
        // transient float4s keep the live set inside the 128-reg budget)
        #pragma unroll
        for (int u = 0; u < 2; ++u)
            #pragma unroll
            for (int t = 0; t < 2; ++t)
                #pragma unroll
                for (int s = 0; s < 2; ++s) {
                    const float* p = z + (rowbase + (size_t)it * 64 + u * 32 + t * 16 + lrow) * 64
                                       + (s << 5) + (lhi << 3);
                    const float4 q0 = *(const float4*)(p);
                    const float4 q1 = *(const float4*)(p + 4);
                    const float vv[8] = {q0.x, q0.y, q0.z, q0.w, q1.x, q1.y, q1.z, q1.w};
                    #pragma unroll
                    for (int j = 0; j < 8; ++j) zh[u][t][s][j] = (_Float16)vv[j];
                }

        // Legendre chain: pA = P1, pB = P2, then ping-pong; P6 ends in pB
        f32x4 pA[2][2][4], pB[2][2][4];
        // mat 0 -> pA  (P1), chained
        __builtin_amdgcn_s_setprio(1);
        #pragma unroll
        for (int f = 0; f < 4; ++f) {
            const int fr0 = f, fr1 = 4 + f;
            const f16x8 bh0 = *(const f16x8*)(smem + BH_OFF + fr0 * 1024 + lane * 16);
            const f16x8 bh1 = *(const f16x8*)(smem + BH_OFF + fr1 * 1024 + lane * 16);
            #pragma unroll
            for (int u = 0; u < 2; ++u)
                #pragma unroll
                for (int t = 0; t < 2; ++t) {
                    f32x4 a = {0.f, 0.f, 0.f, 0.f};
                    a = __builtin_amdgcn_mfma_f32_16x16x32_f16(zh[u][t][0], bh0, a, 0, 0, 0);
                    a = __builtin_amdgcn_mfma_f32_16x16x32_f16(zh[u][t][1], bh1, a, 0, 0, 0);
                    pA[u][t][f] = a;
                }
        }
        // mat 1 -> pB = W2*pA - 0.5  (P2; P0 = ones)
        #pragma unroll
        for (int f = 0; f < 4; ++f) {
            const int fr0 = 8 + f, fr1 = 12 + f;
            const f16x8 bh0 = *(const f16x8*)(smem + BH_OFF + fr0 * 1024 + lane * 16);
            const f16x8 bh1 = *(const f16x8*)(smem + BH_OFF + fr1 * 1024 + lane * 16);
            #pragma unroll
            for (int u = 0; u < 2; ++u)
                #pragma unroll
                for (int t = 0; t < 2; ++t) {
                    f32x4 a = {0.f, 0.f, 0.f, 0.f};
                    a = __builtin_amdgcn_mfma_f32_16x16x32_f16(zh[u][t][0], bh0, a, 0, 0, 0);
                    a = __builtin_amdgcn_mfma_f32_16x16x32_f16(zh[u][t][1], bh1, a, 0, 0, 0);
                    #pragma unroll
                    for (int r = 0; r < 4; ++r)
                        pB[u][t][f][r] = a[r] * pA[u][t][f][r] - 0.5f;
                }
        }
        __builtin_amdgcn_s_setprio(0);
        leg_step(2, 2.f / 3.f, pB, pA);   // P3
        leg_step(3, 3.f / 4.f, pA, pB);   // P4
        leg_step(4, 4.f / 5.f, pB, pA);   // P5
        leg_step(5, 5.f / 6.f, pA, pB);   // P6 = pB

        // ---------------- epilogue: out = P6 @ C^T + beta (single-term) -----
        s16x8 ch[2][2];   // [s][fo]
        #pragma unroll
        for (int s = 0; s < 2; ++s)
            #pragma unroll
            for (int fo = 0; fo < 2; ++fo)
                ch[s][fo] = *(const s16x8*)(smem + CF_OFF + ((s << 1) + fo) * 1024 + lane * 16);
        #pragma unroll
        for (int u = 0; u < 2; ++u)
            #pragma unroll
            for (int t = 0; t < 2; ++t) {
                // transpose P6 (C/D layout) -> A-op layout via XOR-swizzled scratch
                #pragma unroll
                for (int f = 0; f < 4; ++f)
                    #pragma unroll
                    for (int r = 0; r < 4; ++r) {
                        const int row = lhi * 4 + r;
                        const int k   = (f << 4) + lrow;
                        const int g4  = (k >> 2) ^ row;        // group swizzle
                        scr[row * 64 + g4 * 4 + (k & 3)] = pB[u][t][f][r];
                    }
                s16x8 p6h[2];
                #pragma unroll
                for (int s = 0; s < 2; ++s) {
                    const int g0 = lhi * 2 + s * 8;
                    const float4 q0 = *(const float4*)(scr + lrow * 64 + ((g0)     ^ lrow) * 4);
                    const float4 q1 = *(const float4*)(scr + lrow * 64 + ((g0 + 1) ^ lrow) * 4);
                    const float vv[8] = {q0.x, q0.y, q0.z, q0.w, q1.x, q1.y, q1.z, q1.w};
                    #pragma unroll
                    for (int j = 0; j < 8; ++j) p6h[s][j] = (short)f2bf(vv[j]);
                }
                #pragma unroll
                for (int fo = 0; fo < 2; ++fo) {
                    f32x4 o = {0.f, 0.f, 0.f, 0.f};
                    o = __builtin_amdgcn_mfma_f32_16x16x32_bf16(p6h[0], ch[0][fo], o, 0, 0, 0);
                    o = __builtin_amdgcn_mfma_f32_16x16x32_bf16(p6h[1], ch[1][fo], o, 0, 0, 0);
                    const float bb = fo ? beta1 : beta0;
                    const size_t r0 = rowbase + (size_t)it * 64 + u * 32 + t * 16 + lhi * 4;
                    #pragma unroll
                    for (int r = 0; r < 4; ++r)
                        out[(r0 + r) * 32 + (fo << 4) + lrow] = o[r] + bb;
                }
            }
    }
}

extern "C" void kernel_launch(void* const* d_in, const int* in_sizes, int n_in,
                              void* d_out, int out_size, void* d_ws, size_t ws_size,
                              hipStream_t stream) {
    const float* z    = (const float*)d_in[0];
    const float* T    = (const float*)d_in[1];
    const float* C    = (const float*)d_in[2];
    const float* beta = (const float*)d_in[3];
    float* out = (float*)d_out;
    (void)in_sizes; (void)n_in; (void)out_size; (void)d_ws; (void)ws_size;

    hipFuncSetAttribute((const void*)leg_mfma,
                        hipFuncAttributeMaxDynamicSharedMemorySize, SMEM_BYTES);
    leg_mfma<<<BLOCKS, THREADS, SMEM_BYTES, stream>>>(z, T, C, beta, out);
}

// Round 18
// 47.319 us; speedup vs baseline: 1.2671x; 1.0912x over previous
//
#include <hip/hip_runtime.h>

// Legendre2 v17b: v17 with the cvt_pkrtz type fixed (__fp16x2 return type).
//  (1) SCALED RECURRENCE: Q_i = P_i/c_i, c_i = b_i*c_{i-2}
//      (c = 1,1,1/2,2/3,3/8,8/15,5/16). Fold becomes Q_i = a (.) Q_{i-1}
//      - Q_{i-2}: ONE v_fma (neg modifier) per element, b-multiply gone.
//      s_i = c_{i-1}/c_i folded into the A-table per-matrix scale
//      (x1, x2, x3/4, x16/9, x45/64, x128/75); c_6 = 5/16 folded into C.
//  (2) cvt_pkrtz packed f32->f16 for z (2 elems/inst, RTZ).
// Everything else = v16: 256 blk x 512 thr, 2-tile B-frag sharing, chained
// k-half MFMA, setprio, single-term f16 chain + bf16 epilogue.
// N=524288, D=64, K=64, O=32, DEGREE=6.

typedef _Float16 f16x8 __attribute__((ext_vector_type(8)));
typedef __fp16   h16x2 __attribute__((ext_vector_type(2)));
typedef short    s16x8 __attribute__((ext_vector_type(8)));
typedef float    f32x4 __attribute__((ext_vector_type(4)));

#define NN      524288
#define BLOCKS  256
#define THREADS 512
#define NWAVES  8
#define NITER   4                        // 4 x 64-row (2-tile) passes per wave

// LDS byte offsets
#define BH_OFF    0                      // 48 frags * 1 KB (f16 of A, scaled)
#define CF_OFF    49152                  // 4 frags * 1 KB (bf16 of c6*C)
#define SCALE_OFF 53248                  // 384 f32 scales
#define SCR_OFF   54784                  // 8 waves * 4 KB transpose scratch
#define SMEM_BYTES (SCR_OFF + NWAVES * 4096)   // 87552 B

__device__ __forceinline__ unsigned short f2bf(float x) {
    unsigned u = __builtin_bit_cast(unsigned, x);
    return (unsigned short)((u + 0x7FFFu + ((u >> 16) & 1u)) >> 16);
}

__global__ __launch_bounds__(THREADS) void leg_mfma(
    const float* __restrict__ z, const float* __restrict__ T,
    const float* __restrict__ Cm, const float* __restrict__ beta,
    float* __restrict__ out)
{
    extern __shared__ char smem[];
    float* scale_s = (float*)(smem + SCALE_OFF);
    const int tid  = (int)threadIdx.x;
    const int lane = tid & 63;
    const int wv   = tid >> 6;
    const int lrow = lane & 15;          // row (A-op) / col (C/D) index
    const int lhi  = lane >> 4;          // 0..3

    // ---------- phase A: per-row scales with recurrence scaling folded in ---
    // smul[i] = coef_i * s_i  (s_i = c_{i-1}/c_i):
    //   mat0: 1 (T1 raw);  mat1: (3/2)*2 = 3;  mat2: (5/3)*(3/4) = 5/4;
    //   mat3: (7/4)*(16/9) = 28/9;  mat4: (9/5)*(45/64) = 81/64;
    //   mat5: (11/6)*(128/75) = 704/225.
    if (tid < 384) {
        const int mat = tid >> 6, kc = tid & 63;
        const float4* tr = (const float4*)(T + (size_t)((mat << 6) + kc) * 64);
        float s = 0.f;
        #pragma unroll
        for (int q = 0; q < 16; ++q) { float4 v = tr[q]; s += v.x + v.y + v.z + v.w; }
        const float smul[6] = {1.f, 3.f, 1.25f, 28.f / 9.f, 81.f / 64.f, 704.f / 225.f};
        const float sc = (mat == 0) ? 1.f : smul[mat] / s;
        scale_s[tid] = sc;
    }
    __syncthreads();

    // ---------- phase B: build B-operand frags of A (f16, scaled) -----------
    for (int g = tid; g < 3072; g += THREADS) {
        const int mat = g >> 9;
        const int s   = (g >> 8) & 1;
        const int f   = (g >> 6) & 3;
        const int l   = g & 63;
        const int kc  = (l & 15) + (f << 4);
        const int d0  = ((l >> 4) << 3) + (s << 5);
        const float sc = scale_s[(mat << 6) + kc];
        const float* src = T + (size_t)((mat << 6) + kc) * 64 + d0;
        const float4 v0 = *(const float4*)(src);
        const float4 v1 = *(const float4*)(src + 4);
        const float vv[8] = {v0.x, v0.y, v0.z, v0.w, v1.x, v1.y, v1.z, v1.w};
        f16x8 hi;
        #pragma unroll
        for (int j = 0; j < 8; ++j) hi[j] = (_Float16)(vv[j] * sc);
        const int fr = (((mat << 1) + s) << 2) + f;
        *(f16x8*)(smem + BH_OFF + fr * 1024 + l * 16) = hi;
    }
    // C-operand frags (bf16, scaled by c6 = 5/16)
    if (tid < 256) {
        const int s  = (tid >> 7) & 1;
        const int fo = (tid >> 6) & 1;
        const int l  = tid & 63;
        const int o  = (l & 15) + (fo << 4);
        const int k0 = ((l >> 4) << 3) + (s << 5);
        const float* src = Cm + (size_t)o * 64 + k0;
        const float4 v0 = *(const float4*)src;
        const float4 v1 = *(const float4*)(src + 4);
        const float vv[8] = {v0.x, v0.y, v0.z, v0.w, v1.x, v1.y, v1.z, v1.w};
        s16x8 fr;
        #pragma unroll
        for (int j = 0; j < 8; ++j) fr[j] = (short)f2bf(vv[j] * 0.3125f);
        *(s16x8*)(smem + CF_OFF + ((s << 1) + fo) * 1024 + l * 16) = fr;
    }
    __syncthreads();

    // ---------- main: each wave owns 256 rows, 4 iters of 64 rows -----------
    const int    gw      = blockIdx.x * NWAVES + wv;
    const size_t rowbase = (size_t)gw * 256;
    float* scr = (float*)(smem + SCR_OFF + wv * 4096);

    const float beta0 = beta[lrow];
    const float beta1 = beta[16 + lrow];

    f16x8 zh[2][2][2];                   // [u][t][s]

    // one Legendre level (scaled): PT := a (.) PC - PT  (single fma, neg mod)
    auto leg_step = [&](int mat, f32x4 (&PC)[2][2][4], f32x4 (&PT)[2][2][4]) {
        __builtin_amdgcn_s_setprio(1);
        #pragma unroll
        for (int f = 0; f < 4; ++f) {
            const int fr0 = mat * 8 + f;       // s=0
            const int fr1 = mat * 8 + 4 + f;   // s=1
            const f16x8 bh0 = *(const f16x8*)(smem + BH_OFF + fr0 * 1024 + lane * 16);
            const f16x8 bh1 = *(const f16x8*)(smem + BH_OFF + fr1 * 1024 + lane * 16);
            #pragma unroll
            for (int u = 0; u < 2; ++u)
                #pragma unroll
                for (int t = 0; t < 2; ++t) {
                    f32x4 a = {0.f, 0.f, 0.f, 0.f};
                    a = __builtin_amdgcn_mfma_f32_16x16x32_f16(zh[u][t][0], bh0, a, 0, 0, 0);
                    a = __builtin_amdgcn_mfma_f32_16x16x32_f16(zh[u][t][1], bh1, a, 0, 0, 0);
                    #pragma unroll
                    for (int r = 0; r < 4; ++r)
                        PT[u][t][f][r] = a[r] * PC[u][t][f][r] - PT[u][t][f][r];
                }
        }
        __builtin_amdgcn_s_setprio(0);
    };

    for (int it = 0; it < NITER; ++it) {
        // load + convert z (packed RTZ: 4 cvt_pkrtz per 8 elems)
        #pragma unroll
        for (int u = 0; u < 2; ++u)
            #pragma unroll
            for (int t = 0; t < 2; ++t)
                #pragma unroll
                for (int s = 0; s < 2; ++s) {
                    const float* p = z + (rowbase + (size_t)it * 64 + u * 32 + t * 16 + lrow) * 64
                                       + (s << 5) + (lhi << 3);
                    const float4 q0 = *(const float4*)(p);
                    const float4 q1 = *(const float4*)(p + 4);
                    union { f16x8 v; h16x2 h[4]; } uz;
                    uz.h[0] = __builtin_amdgcn_cvt_pkrtz(q0.x, q0.y);
                    uz.h[1] = __builtin_amdgcn_cvt_pkrtz(q0.z, q0.w);
                    uz.h[2] = __builtin_amdgcn_cvt_pkrtz(q1.x, q1.y);
                    uz.h[3] = __builtin_amdgcn_cvt_pkrtz(q1.z, q1.w);
                    zh[u][t][s] = uz.v;
                }

        // Scaled Legendre chain: pA = Q1, pB = Q2, ping-pong; Q6 ends in pB
        f32x4 pA[2][2][4], pB[2][2][4];
        // mat 0 -> pA  (Q1), chained
        __builtin_amdgcn_s_setprio(1);
        #pragma unroll
        for (int f = 0; f < 4; ++f) {
            const int fr0 = f, fr1 = 4 + f;
            const f16x8 bh0 = *(const f16x8*)(smem + BH_OFF + fr0 * 1024 + lane * 16);
            const f16x8 bh1 = *(const f16x8*)(smem + BH_OFF + fr1 * 1024 + lane * 16);
            #pragma unroll
            for (int u = 0; u < 2; ++u)
                #pragma unroll
                for (int t = 0; t < 2; ++t) {
                    f32x4 a = {0.f, 0.f, 0.f, 0.f};
                    a = __builtin_amdgcn_mfma_f32_16x16x32_f16(zh[u][t][0], bh0, a, 0, 0, 0);
                    a = __builtin_amdgcn_mfma_f32_16x16x32_f16(zh[u][t][1], bh1, a, 0, 0, 0);
                    pA[u][t][f] = a;
                }
        }
        // mat 1 -> pB = Q2 = a (.) Q1 - 1  (Q0 = ones; inline -1.0)
        #pragma unroll
        for (int f = 0; f < 4; ++f) {
            const int fr0 = 8 + f, fr1 = 12 + f;
            const f16x8 bh0 = *(const f16x8*)(smem + BH_OFF + fr0 * 1024 + lane * 16);
            const f16x8 bh1 = *(const f16x8*)(smem + BH_OFF + fr1 * 1024 + lane * 16);
            #pragma unroll
            for (int u = 0; u < 2; ++u)
                #pragma unroll
                for (int t = 0; t < 2; ++t) {
                    f32x4 a = {0.f, 0.f, 0.f, 0.f};
                    a = __builtin_amdgcn_mfma_f32_16x16x32_f16(zh[u][t][0], bh0, a, 0, 0, 0);
                    a = __builtin_amdgcn_mfma_f32_16x16x32_f16(zh[u][t][1], bh1, a, 0, 0, 0);
                    #pragma unroll
                    for (int r = 0; r < 4; ++r)
                        pB[u][t][f][r] = a[r] * pA[u][t][f][r] - 1.0f;
                }
        }
        __builtin_amdgcn_s_setprio(0);
        leg_step(2, pB, pA);   // Q3
        leg_step(3, pA, pB);   // Q4
        leg_step(4, pB, pA);   // Q5
        leg_step(5, pA, pB);   // Q6 = pB

        // ---------------- epilogue: out = Q6 @ (c6*C)^T + beta --------------
        s16x8 ch[2][2];   // [s][fo]
        #pragma unroll
        for (int s = 0; s < 2; ++s)
            #pragma unroll
            for (int fo = 0; fo < 2; ++fo)
                ch[s][fo] = *(const s16x8*)(smem + CF_OFF + ((s << 1) + fo) * 1024 + lane * 16);
        #pragma unroll
        for (int u = 0; u < 2; ++u)
            #pragma unroll
            for (int t = 0; t < 2; ++t) {
                // transpose Q6 (C/D layout) -> A-op layout via XOR-swizzled scratch
                #pragma unroll
                for (int f = 0; f < 4; ++f)
                    #pragma unroll
                    for (int r = 0; r < 4; ++r) {
                        const int row = lhi * 4 + r;
                        const int k   = (f << 4) + lrow;
                        const int g4  = (k >> 2) ^ row;        // group swizzle
                        scr[row * 64 + g4 * 4 + (k & 3)] = pB[u][t][f][r];
                    }
                s16x8 p6h[2];
                #pragma unroll
                for (int s = 0; s < 2; ++s) {
                    const int g0 = lhi * 2 + s * 8;
                    const float4 q0 = *(const float4*)(scr + lrow * 64 + ((g0)     ^ lrow) * 4);
                    const float4 q1 = *(const float4*)(scr + lrow * 64 + ((g0 + 1) ^ lrow) * 4);
                    const float vv[8] = {q0.x, q0.y, q0.z, q0.w, q1.x, q1.y, q1.z, q1.w};
                    #pragma unroll
                    for (int j = 0; j < 8; ++j) p6h[s][j] = (short)f2bf(vv[j]);
                }
                #pragma unroll
                for (int fo = 0; fo < 2; ++fo) {
                    f32x4 o = {0.f, 0.f, 0.f, 0.f};
                    o = __builtin_amdgcn_mfma_f32_16x16x32_bf16(p6h[0], ch[0][fo], o, 0, 0, 0);
                    o = __builtin_amdgcn_mfma_f32_16x16x32_bf16(p6h[1], ch[1][fo], o, 0, 0, 0);
                    const float bb = fo ? beta1 : beta0;
                    const size_t r0 = rowbase + (size_t)it * 64 + u * 32 + t * 16 + lhi * 4;
                    #pragma unroll
                    for (int r = 0; r < 4; ++r)
                        out[(r0 + r) * 32 + (fo << 4) + lrow] = o[r] + bb;
                }
            }
    }
}

extern "C" void kernel_launch(void* const* d_in, const int* in_sizes, int n_in,
                              void* d_out, int out_size, void* d_ws, size_t ws_size,
                              hipStream_t stream) {
    const float* z    = (const float*)d_in[0];
    const float* T    = (const float*)d_in[1];
    const float* C    = (const float*)d_in[2];
    const float* beta = (const float*)d_in[3];
    float* out = (float*)d_out;
    (void)in_sizes; (void)n_in; (void)out_size; (void)d_ws; (void)ws_size;

    hipFuncSetAttribute((const void*)leg_mfma,
                        hipFuncAttributeMaxDynamicSharedMemorySize, SMEM_BYTES);
    leg_mfma<<<BLOCKS, THREADS, SMEM_BYTES, stream>>>(z, T, C, beta, out);
}